// Round 9
// baseline (272.596 us; speedup 1.0000x reference)
//
#include <hip/hip_runtime.h>
#include <stdint.h>
#include <stddef.h>

// ---------------- problem constants ----------------
// B=2048, F0=39, D=16, layers 128/128/128, xk halves to 64 after each layer.
// Factored form: y_h[s,d] = sum_k W[h,k,s]*xk[b,k,d] (MFMA: A=W static, B=xk
// h-invariant -> register-cached per layer); z[b,s,d] = sum_h x0[b,h,d]*y_h[s,d].
// R20: kill the fixed ~60us/iteration two-launch overhead. Ledger R0-R19:
// dur_us - main_us = 57-64us REGARDLESS of main structure; prepass compute is
// ~3-5us -> ~55us is dispatch + inter-kernel drain. Fix: ONE kernel. Blocks
// 0..116 convert one (L,h) W-unit each (1024 thr x 8 vals), threadfence +
// release-store a MAGIC flag in d_ws tail; all blocks run the (wt-free) LDS
// prologue, then acquire-spin on the 117 flags (device scope, Guideline 16),
// threadfence (invalidate stale/poisoned lines), and run the R18 main loop
// unchanged. All 256 blocks co-resident (grid <= CU count) -> no deadlock.
// Stale-flag case (d_ws not re-poisoned) is benign: wt rewrite is bit-
// identical (same weights). Host falls back to two-kernel if ws_size small.
// Main loop = R18 champion exactly (VGPR 60, no spill, no cold dispatch;
// R19's unroll3+wpe(4,4) spilled -> 178us dispatch-0, rejected).
#define F0N  39
#define SN   128
#define NB   8             // batches per block
#define X0TS 45            // f32 stride of X0T row (b,d): 39+6 pad, odd => conflict-free
#define XKTS 72            // u16 stride of XKT row (b,d): 64+8 pad, 16B-aligned
#define WBLK 8192          // u16 per (L,h) W block: 8 s-tiles x 2 chunks x 512
#define NHB2 234           // 3*39*2 prepass blocks (fallback path)
#define NFLAGS 117         // conversion units = 3*39 (L,h)
#define WT_U16 (NFLAGS * WBLK)      // 958,464 u16
#define WT_BYTES (WT_U16 * 2)       // 1,916,928 B
#define FMAGIC 0x9E3779B1u

typedef __attribute__((ext_vector_type(8))) short short8;   // MFMA A/B operand
typedef __attribute__((ext_vector_type(4))) float floatx4;  // MFMA accumulator
typedef __attribute__((ext_vector_type(4))) uint32_t uint32x4;

__device__ __forceinline__ uint16_t f2bf(float f) {         // RNE f32->bf16
  uint32_t u = __float_as_uint(f);
  u += 0x7fffu + ((u >> 16) & 1u);
  return (uint16_t)(u >> 16);
}

// ---------------- fallback pre-pass (two-kernel path) ----------------
// One block per (L,h,ch). Output layout identical to R6-R19 (verified):
//   wt[(L*39+h)*WBLK + (st*2+ch)*512 + lane*8 + j],
//   value = W[h][k=ch*32+quad*8+j][s=st*16+l16].
__global__ __launch_bounds__(256) void cin_prepass(
    const float* __restrict__ w0, const float* __restrict__ w1,
    const float* __restrict__ w2, uint16_t* __restrict__ wt) {
  __shared__ float T[32 * 132];               // [k_local][s], +4 pad floats/row
  const int bc = blockIdx.x;                  // 0..233
  const int ch = bc & 1;
  const int lh = bc >> 1;                     // 0..116
  const int L = lh / F0N;
  const int h = lh - L * F0N;
  const float* W = (L == 0) ? w0 : ((L == 1) ? w1 : w2);
  const int fk = (L == 0) ? 39 : 64;
  const int tid = threadIdx.x;

  for (int e = tid; e < 4096; e += 256) {     // coalesced fp32 read
    int kc = e >> 7, s = e & 127;
    int k = ch * 32 + kc;
    T[kc * 132 + s] = (k < fk) ? W[(h * fk + k) * SN + s] : 0.0f;
  }
  __syncthreads();
  uint32_t* dst = (uint32_t*)(wt + (size_t)lh * WBLK);
  for (int i = tid; i < 2048; i += 256) {     // coalesced u32 writes, frag order
    int st = i >> 8, w = i & 255;
    int ln = w >> 2, jp = w & 3;
    int quad = ln >> 4, l16 = ln & 15;
    int k0 = quad * 8 + jp * 2;               // local k within this half
    int s = st * 16 + l16;
    dst[(size_t)(st * 2 + ch) * 256 + w] =
        (uint32_t)f2bf(T[k0 * 132 + s]) | ((uint32_t)f2bf(T[(k0 + 1) * 132 + s]) << 16);
  }
}

// ---------------- fused kernel: W-convert + handshake + main ----------------
// 256 blocks x 1024 threads (16 waves), 1 block/CU, 4 waves/SIMD.
// Main partition (R18): wave (st,bg): s-tile [st*16,st*16+16) x batches
// [bg*4,bg*4+4). Per layer: Bf reg-cached; per h: dist-1 W prefetch (SALU ih
// base), 4 scalar xs ds_reads (odd stride, conflict-free), 8 MFMA + 16 fmac.
__global__ __launch_bounds__(1024) void cin_fused(
    const float* __restrict__ x,       // (2048, 39, 16) fp32
    const float* __restrict__ w0, const float* __restrict__ w1,
    const float* __restrict__ w2,
    const float* __restrict__ bias0, const float* __restrict__ bias1,
    const float* __restrict__ bias2,
    uint16_t* __restrict__ wt,         // d_ws: wt (1.9MB) + 117 flag u32s
    float* __restrict__ out) {         // (2048, 256) fp32

  __shared__ __align__(16) float    X0T[NB * 16 * X0TS];  // x0[b][d][h] f32, 23040 B
  __shared__ __align__(16) uint16_t XKT[NB * 16 * XKTS];  // xk[b][d][k] bf16, 18432 B

  uint32_t* flags = (uint32_t*)(wt + WT_U16);
  const int tid  = threadIdx.x;

  // ---- phase A: W conversion (blocks 0..116, one (L,h) unit each) ----
  // Same verified layout as cin_prepass: u32 idx within unit =
  // (st*2+ch)*256 + ln*4 + jp, packing k = ch*32 + quad*8 + 2jp (+1 in hi).
  if (blockIdx.x < NFLAGS) {
    const int lh = blockIdx.x;
    const int Lc = lh / F0N;
    const int hc = lh - Lc * F0N;
    const float* W = (Lc == 0) ? w0 : ((Lc == 1) ? w1 : w2);
    const int fk = (Lc == 0) ? 39 : 64;
    const int stc  = tid >> 7;          // 0..7
    const int chc  = (tid >> 6) & 1;
    const int lnc  = tid & 63;
    const int qc   = lnc >> 4;
    const int l16c = lnc & 15;
    const float* Wh = W + (size_t)hc * fk * SN + (stc * 16 + l16c);
    uint32x4 o;
#pragma unroll
    for (int jp = 0; jp < 4; ++jp) {
      int k0 = chc * 32 + qc * 8 + jp * 2;
      uint32_t lo = (k0 < fk)     ? (uint32_t)f2bf(Wh[(size_t)k0 * SN])       : 0u;
      uint32_t hi = (k0 + 1 < fk) ? (uint32_t)f2bf(Wh[(size_t)(k0 + 1) * SN]) : 0u;
      o[jp] = lo | (hi << 16);
    }
    uint32_t* dst = (uint32_t*)wt + (size_t)lh * 4096 + (stc * 2 + chc) * 256 + lnc * 4;
    *(uint32x4*)dst = o;
    __threadfence();                    // writes agent-visible before flag
    __syncthreads();                    // all threads of unit done
    if (tid == 0)
      __hip_atomic_store(&flags[lh], FMAGIC, __ATOMIC_RELEASE, __HIP_MEMORY_SCOPE_AGENT);
  }

  // ---- phase B: LDS prologue (wt-independent; overlaps others' conversion) ----
  const int lane = tid & 63;
  const int wave = tid >> 6;           // 0..15
  const int st   = wave >> 1;          // s-tile 0..7
  const int bg   = wave & 1;           // batch group 0..1
  const int l16  = lane & 15;          // = d (output col)
  const int quad = lane >> 4;
  const int bbase = blockIdx.x * NB;

  {
    float* p = X0T;
#pragma unroll
    for (int i = 0; i < 6; i++) { int e = tid + 1024 * i; if (e < NB * 16 * X0TS) p[e] = 0.f; }
    uint32_t* q = (uint32_t*)XKT;
#pragma unroll
    for (int i = 0; i < 5; i++) { int e = tid + 1024 * i; if (e < NB * 16 * XKTS / 2) q[e] = 0u; }
  }
  __syncthreads();

#pragma unroll
  for (int it = 0; it < 5; ++it) {
    int e = tid + it * 1024;           // e = (b*39 + h)*16 + d, total 4992
    if (e < NB * F0N * 16) {
      float v = x[(size_t)bbase * (F0N * 16) + e];
      int d = e & 15, p = e >> 4;
      int b = p / F0N, h = p - b * F0N;
      X0T[(b * 16 + d) * X0TS + h] = v;
    }
  }
  __syncthreads();

  if (tid < 512) {                     // layer-0 XKT build
    int b = tid >> 6, d = (tid >> 2) & 15, kg = tid & 3;
    const float* src = &X0T[(b * 16 + d) * X0TS];
    uint32_t* drow = (uint32_t*)&XKT[(b * 16 + d) * XKTS + kg * 16];
#pragma unroll
    for (int i2 = 0; i2 < 8; i2++) {
      int k0 = kg * 16 + i2 * 2;
      uint32_t lo = (k0 < 39)     ? (uint32_t)f2bf(src[k0])     : 0u;
      uint32_t hi = (k0 + 1 < 39) ? (uint32_t)f2bf(src[k0 + 1]) : 0u;
      drow[i2] = lo | (hi << 16);
    }
  }
  __syncthreads();   // XKT build visible for Bf loads

  // ---- phase C: wait for all W units (acquire, device scope) ----
  if (tid < NFLAGS) {
    while (__hip_atomic_load(&flags[tid], __ATOMIC_ACQUIRE, __HIP_MEMORY_SCOPE_AGENT) != FMAGIC)
      __builtin_amdgcn_s_sleep(2);
  }
  __syncthreads();
  __threadfence();   // invalidate any stale (poison-era) wt lines before reads

  // ---- phase D: R18 main loop, unchanged ----
  const int stlane = st * 1024 + lane * 8;   // bg-pair waves share W lines (L1)

  short8 Wc0 = *(const short8*)(wt + stlane);
  short8 Wc1 = *(const short8*)(wt + stlane + 512);

  int ih = 0;                          // flat weight-block index = L*39 + h
#pragma unroll 1
  for (int L = 0; L < 3; ++L) {
    short8 Bf0[4], Bf1[4];             // B-frags, h-invariant; b = bg*4 + bi
#pragma unroll
    for (int bi = 0; bi < 4; ++bi) {
      const uint16_t* r = XKT + ((bg * 4 + bi) * 16 + l16) * XKTS + quad * 8;
      Bf0[bi] = *(const short8*)r;          // k 0..31 chunk
      Bf1[bi] = *(const short8*)(r + 32);   // k 32..63 chunk
    }
    const float* bp = (L == 0) ? bias0 : ((L == 1) ? bias1 : bias2);
    float bvr[4];
#pragma unroll
    for (int r = 0; r < 4; ++r) bvr[r] = bp[st * 16 + quad * 4 + r];

    floatx4 z[4] = {};
    const floatx4 zero4 = {0.f, 0.f, 0.f, 0.f};

#pragma unroll 1
    for (int h = 0; h < 39; ++h, ++ih) {
      // dist-1 prefetch; uniform SALU base (ih+1 at h=38 IS next layer's h0)
      int ihn = ih + 1;
      if (ihn > 116) ihn = 116;
      const uint16_t* wb = wt + (size_t)ihn * WBLK + stlane;
      short8 Wn0 = *(const short8*)(wb);
      short8 Wn1 = *(const short8*)(wb + 512);

      float xs[4];                     // conflict-free (odd stride)
#pragma unroll
      for (int bi = 0; bi < 4; ++bi)
        xs[bi] = X0T[((bg * 4 + bi) * 16 + l16) * X0TS + h];

#pragma unroll
      for (int bi = 0; bi < 4; ++bi) {
        floatx4 y = __builtin_amdgcn_mfma_f32_16x16x32_bf16(Wc0, Bf0[bi], zero4, 0, 0, 0);
        y = __builtin_amdgcn_mfma_f32_16x16x32_bf16(Wc1, Bf1[bi], y, 0, 0, 0);
#pragma unroll
        for (int r = 0; r < 4; ++r) z[bi][r] += xs[bi] * y[r];
      }
      Wc0 = Wn0;
      Wc1 = Wn1;
    }

    // ---- epilogue: bias+relu; xk handoff; sum_d (over l16) -> out ----
#pragma unroll
    for (int bi = 0; bi < 4; ++bi) {
      const int b = bg * 4 + bi;
#pragma unroll
      for (int r = 0; r < 4; ++r) {
        float t = fmaxf(z[bi][r] + bvr[r], 0.f);
        if (L < 2 && st < 4)               // xk = relu(z)[:, :64]; k = s < 64
          XKT[(b * 16 + l16) * XKTS + st * 16 + quad * 4 + r] = f2bf(t);
        float s4 = t;                       // reduce over d = l16 (bits 0..3)
        s4 += __shfl_xor(s4, 1);
        s4 += __shfl_xor(s4, 2);
        s4 += __shfl_xor(s4, 4);
        s4 += __shfl_xor(s4, 8);
        if (l16 == 0) {
          int s = st * 16 + quad * 4 + r;
          // concat: L0 s64:128 -> 0:64 ; L1 s64:128 -> 64:128 ; L2 s -> 128:256
          if (L == 2)       out[(size_t)(bbase + b) * 256 + 128 + s] = s4;
          else if (s >= 64) out[(size_t)(bbase + b) * 256 + L * 64 + (s - 64)] = s4;
        }
      }
    }
    if (L < 2) __syncthreads();   // handoff writes visible before next-layer Bf loads
  }
}

// ---------------- fallback main (two-kernel path), R18 exact ----------------
__global__ __launch_bounds__(1024) void cin_main(
    const float* __restrict__ x,
    const float* __restrict__ bias0, const float* __restrict__ bias1,
    const float* __restrict__ bias2,
    const uint16_t* __restrict__ wt,
    float* __restrict__ out) {

  __shared__ __align__(16) float    X0T[NB * 16 * X0TS];
  __shared__ __align__(16) uint16_t XKT[NB * 16 * XKTS];

  const int tid  = threadIdx.x;
  const int lane = tid & 63;
  const int wave = tid >> 6;
  const int st   = wave >> 1;
  const int bg   = wave & 1;
  const int l16  = lane & 15;
  const int quad = lane >> 4;
  const int bbase = blockIdx.x * NB;

  {
    float* p = X0T;
#pragma unroll
    for (int i = 0; i < 6; i++) { int e = tid + 1024 * i; if (e < NB * 16 * X0TS) p[e] = 0.f; }
    uint32_t* q = (uint32_t*)XKT;
#pragma unroll
    for (int i = 0; i < 5; i++) { int e = tid + 1024 * i; if (e < NB * 16 * XKTS / 2) q[e] = 0u; }
  }
  __syncthreads();

#pragma unroll
  for (int it = 0; it < 5; ++it) {
    int e = tid + it * 1024;
    if (e < NB * F0N * 16) {
      float v = x[(size_t)bbase * (F0N * 16) + e];
      int d = e & 15, p = e >> 4;
      int b = p / F0N, h = p - b * F0N;
      X0T[(b * 16 + d) * X0TS + h] = v;
    }
  }
  __syncthreads();

  if (tid < 512) {
    int b = tid >> 6, d = (tid >> 2) & 15, kg = tid & 3;
    const float* src = &X0T[(b * 16 + d) * X0TS];
    uint32_t* drow = (uint32_t*)&XKT[(b * 16 + d) * XKTS + kg * 16];
#pragma unroll
    for (int i2 = 0; i2 < 8; i2++) {
      int k0 = kg * 16 + i2 * 2;
      uint32_t lo = (k0 < 39)     ? (uint32_t)f2bf(src[k0])     : 0u;
      uint32_t hi = (k0 + 1 < 39) ? (uint32_t)f2bf(src[k0 + 1]) : 0u;
      drow[i2] = lo | (hi << 16);
    }
  }
  __syncthreads();

  const int stlane = st * 1024 + lane * 8;
  short8 Wc0 = *(const short8*)(wt + stlane);
  short8 Wc1 = *(const short8*)(wt + stlane + 512);

  int ih = 0;
#pragma unroll 1
  for (int L = 0; L < 3; ++L) {
    short8 Bf0[4], Bf1[4];
#pragma unroll
    for (int bi = 0; bi < 4; ++bi) {
      const uint16_t* r = XKT + ((bg * 4 + bi) * 16 + l16) * XKTS + quad * 8;
      Bf0[bi] = *(const short8*)r;
      Bf1[bi] = *(const short8*)(r + 32);
    }
    const float* bp = (L == 0) ? bias0 : ((L == 1) ? bias1 : bias2);
    float bvr[4];
#pragma unroll
    for (int r = 0; r < 4; ++r) bvr[r] = bp[st * 16 + quad * 4 + r];

    floatx4 z[4] = {};
    const floatx4 zero4 = {0.f, 0.f, 0.f, 0.f};

#pragma unroll 1
    for (int h = 0; h < 39; ++h, ++ih) {
      int ihn = ih + 1;
      if (ihn > 116) ihn = 116;
      const uint16_t* wb = wt + (size_t)ihn * WBLK + stlane;
      short8 Wn0 = *(const short8*)(wb);
      short8 Wn1 = *(const short8*)(wb + 512);

      float xs[4];
#pragma unroll
      for (int bi = 0; bi < 4; ++bi)
        xs[bi] = X0T[((bg * 4 + bi) * 16 + l16) * X0TS + h];

#pragma unroll
      for (int bi = 0; bi < 4; ++bi) {
        floatx4 y = __builtin_amdgcn_mfma_f32_16x16x32_bf16(Wc0, Bf0[bi], zero4, 0, 0, 0);
        y = __builtin_amdgcn_mfma_f32_16x16x32_bf16(Wc1, Bf1[bi], y, 0, 0, 0);
#pragma unroll
        for (int r = 0; r < 4; ++r) z[bi][r] += xs[bi] * y[r];
      }
      Wc0 = Wn0;
      Wc1 = Wn1;
    }

#pragma unroll
    for (int bi = 0; bi < 4; ++bi) {
      const int b = bg * 4 + bi;
#pragma unroll
      for (int r = 0; r < 4; ++r) {
        float t = fmaxf(z[bi][r] + bvr[r], 0.f);
        if (L < 2 && st < 4)
          XKT[(b * 16 + l16) * XKTS + st * 16 + quad * 4 + r] = f2bf(t);
        float s4 = t;
        s4 += __shfl_xor(s4, 1);
        s4 += __shfl_xor(s4, 2);
        s4 += __shfl_xor(s4, 4);
        s4 += __shfl_xor(s4, 8);
        if (l16 == 0) {
          int s = st * 16 + quad * 4 + r;
          if (L == 2)       out[(size_t)(bbase + b) * 256 + 128 + s] = s4;
          else if (s >= 64) out[(size_t)(bbase + b) * 256 + L * 64 + (s - 64)] = s4;
        }
      }
    }
    if (L < 2) __syncthreads();
  }
}

extern "C" void kernel_launch(void* const* d_in, const int* in_sizes, int n_in,
                              void* d_out, int out_size, void* d_ws, size_t ws_size,
                              hipStream_t stream) {
  (void)in_sizes; (void)n_in; (void)out_size;
  const float* x  = (const float*)d_in[0];
  const float* w0 = (const float*)d_in[1];
  const float* b0 = (const float*)d_in[2];
  const float* w1 = (const float*)d_in[3];
  const float* b1 = (const float*)d_in[4];
  const float* w2 = (const float*)d_in[5];
  const float* b2 = (const float*)d_in[6];
  uint16_t* wt    = (uint16_t*)d_ws;   // wt 1,916,928 B + 117 flag u32s

  if (ws_size >= (size_t)WT_BYTES + NFLAGS * 4) {
    cin_fused<<<256, 1024, 0, stream>>>(x, w0, w1, w2, b0, b1, b2, wt, (float*)d_out);
  } else {
    cin_prepass<<<NHB2, 256, 0, stream>>>(w0, w1, w2, wt);
    cin_main<<<256, 1024, 0, stream>>>(x, b0, b1, b2, wt, (float*)d_out);
  }
}

// Round 10
// 138.013 us; speedup vs baseline: 1.9752x; 1.9752x over previous
//
#include <hip/hip_runtime.h>
#include <stdint.h>
#include <stddef.h>

// ---------------- problem constants ----------------
// B=2048, F0=39, D=16, layers 128/128/128, xk halves to 64 after each layer.
// Factored form: y_h[s,d] = sum_k W[h,k,s]*xk[b,k,d] (MFMA: A=W static, B=xk
// h-invariant -> register-cached per layer); z[b,s,d] = sum_h x0[b,h,d]*y_h[s,d].
// R21: R18 + unroll-3, spill-proofed. Evidence ledger:
//  - R19: unroll3 cut steady main 77.5->74.1 (rotation breaks the per-h WAR
//    on y) but overshot the 64-reg budget by 2 dwords (xsn prefetch + wpe cap)
//    -> 8B/thread scratch -> 178us dispatch-0 scratch-init poisoned the avg.
//  - R20: fused single-kernel ran 223us (cross-XCD handshake thrashes wt L2)
//    BUT proved the fixed overhead is ~49us even with ONE launch -> harness
//    reset() cost; the 2nd launch is only ~6us. Prepass lane closed.
// R21 = R18 exactly + (a) #pragma unroll 3 on the h-loop (39=13x3), (b) bias
// read moved into the epilogue (frees 4 regs across the h-loop), (c) NO xs
// prefetch, NO wpe attribute (R18 default alloc = 60 regs, zero spill).
// Kept: X0TS=45 (conflicts 4.69M->0.69M), flat-ih SALU W walk, h=39 drop,
// grid 256 (1 block/CU; R12/R13: 2 blocks/CU doubles per-CU L1 W demand),
// bg-pair W sharing, dist-1 W register prefetch.
#define F0N  39
#define SN   128
#define NB   8             // batches per block
#define X0TS 45            // f32 stride of X0T row (b,d): 39+6 pad, odd => conflict-free
#define XKTS 72            // u16 stride of XKT row (b,d): 64+8 pad, 16B-aligned
#define WBLK 8192          // u16 per (L,h) W block: 8 s-tiles x 2 chunks x 512
#define NHB2 234           // 3*39*2 prepass blocks (one per (L,h,k-half))

typedef __attribute__((ext_vector_type(8))) short short8;   // MFMA A/B operand
typedef __attribute__((ext_vector_type(4))) float floatx4;  // MFMA accumulator

__device__ __forceinline__ uint16_t f2bf(float f) {         // RNE f32->bf16
  uint32_t u = __float_as_uint(f);
  u += 0x7fffu + ((u >> 16) & 1u);
  return (uint16_t)(u >> 16);
}

// ---------------- pre-pass: W fp32 -> bf16 A-fragment blocks ----------------
// One block per (L,h,ch). Output layout identical to R6-R20 (verified):
//   wt[(L*39+h)*WBLK + (st*2+ch)*512 + lane*8 + j],
//   value = W[h][k=ch*32+quad*8+j][s=st*16+l16].
__global__ __launch_bounds__(256) void cin_prepass(
    const float* __restrict__ w0, const float* __restrict__ w1,
    const float* __restrict__ w2, uint16_t* __restrict__ wt) {
  __shared__ float T[32 * 132];               // [k_local][s], +4 pad floats/row
  const int bc = blockIdx.x;                  // 0..233
  const int ch = bc & 1;
  const int lh = bc >> 1;                     // 0..116
  const int L = lh / F0N;
  const int h = lh - L * F0N;
  const float* W = (L == 0) ? w0 : ((L == 1) ? w1 : w2);
  const int fk = (L == 0) ? 39 : 64;
  const int tid = threadIdx.x;

  for (int e = tid; e < 4096; e += 256) {     // coalesced fp32 read
    int kc = e >> 7, s = e & 127;
    int k = ch * 32 + kc;
    T[kc * 132 + s] = (k < fk) ? W[(h * fk + k) * SN + s] : 0.0f;
  }
  __syncthreads();
  uint32_t* dst = (uint32_t*)(wt + (size_t)lh * WBLK);
  for (int i = tid; i < 2048; i += 256) {     // coalesced u32 writes, frag order
    int st = i >> 8, w = i & 255;
    int ln = w >> 2, jp = w & 3;
    int quad = ln >> 4, l16 = ln & 15;
    int k0 = quad * 8 + jp * 2;               // local k within this half
    int s = st * 16 + l16;
    dst[(size_t)(st * 2 + ch) * 256 + w] =
        (uint32_t)f2bf(T[k0 * 132 + s]) | ((uint32_t)f2bf(T[(k0 + 1) * 132 + s]) << 16);
  }
}

// ---------------- fused main kernel ----------------
// 256 blocks x 1024 threads (16 waves), 1 block/CU, 4 waves/SIMD.
// Block owns NB=8 batches x full s (xk handoff block-local). Wave (st,bg):
// s-tile [st*16,st*16+16) x batches [bg*4, bg*4+4). Per layer: Bf register-
// cached; per h (unroll 3, reg rotation kills the y WAR chain): dist-1 W
// prefetch (SALU ih base), 4 scalar xs ds_reads (odd stride, conflict-free
// broadcast), 8 MFMA + 16 fmac. Flat weight index ih = L*39+h in [0,117);
// prefetch min(ih+1,116) rolls into next layer's h0 at h=38.
// D-layout: D[s=st*16+quad*4+r][d=l16]; sum_d over l16 bits.
__global__ __launch_bounds__(1024) void cin_main(
    const float* __restrict__ x,       // (2048, 39, 16) fp32
    const float* __restrict__ bias0, const float* __restrict__ bias1,
    const float* __restrict__ bias2,
    const uint16_t* __restrict__ wt,   // A-frag bf16 weights (d_ws)
    float* __restrict__ out) {         // (2048, 256) fp32

  __shared__ __align__(16) float    X0T[NB * 16 * X0TS];  // x0[b][d][h] f32, 23040 B
  __shared__ __align__(16) uint16_t XKT[NB * 16 * XKTS];  // xk[b][d][k] bf16, 18432 B

  const int tid  = threadIdx.x;
  const int lane = tid & 63;
  const int wave = tid >> 6;           // 0..15
  const int st   = wave >> 1;          // s-tile 0..7
  const int bg   = wave & 1;           // batch group 0..1
  const int l16  = lane & 15;          // = d (output col)
  const int quad = lane >> 4;
  const int bbase = blockIdx.x * NB;

  // zero X0T (h-pad 39..44 must be 0) and XKT (k-pad for L0)
  {
    float* p = X0T;
#pragma unroll
    for (int i = 0; i < 6; i++) { int e = tid + 1024 * i; if (e < NB * 16 * X0TS) p[e] = 0.f; }
    uint32_t* q = (uint32_t*)XKT;
#pragma unroll
    for (int i = 0; i < 5; i++) { int e = tid + 1024 * i; if (e < NB * 16 * XKTS / 2) q[e] = 0u; }
  }
  __syncthreads();

  // fill X0T[b][d][h] = x[bbase+b][h][d]  (coalesced read, LDS transpose-scatter)
#pragma unroll
  for (int it = 0; it < 5; ++it) {
    int e = tid + it * 1024;           // e = (b*39 + h)*16 + d, total 4992
    if (e < NB * F0N * 16) {
      float v = x[(size_t)bbase * (F0N * 16) + e];
      int d = e & 15, p = e >> 4;
      int b = p / F0N, h = p - b * F0N;
      X0T[(b * 16 + d) * X0TS + h] = v;
    }
  }
  __syncthreads();

  // build layer-0 XKT[b][d][k] = bf16(x0[b][k][d]) for k<39, 0 for k in [39,64)
  if (tid < 512) {
    int b = tid >> 6, d = (tid >> 2) & 15, kg = tid & 3;
    const float* src = &X0T[(b * 16 + d) * X0TS];
    uint32_t* drow = (uint32_t*)&XKT[(b * 16 + d) * XKTS + kg * 16];
#pragma unroll
    for (int i2 = 0; i2 < 8; i2++) {
      int k0 = kg * 16 + i2 * 2;
      uint32_t lo = (k0 < 39)     ? (uint32_t)f2bf(src[k0])     : 0u;
      uint32_t hi = (k0 + 1 < 39) ? (uint32_t)f2bf(src[k0 + 1]) : 0u;
      drow[i2] = lo | (hi << 16);
    }
  }
  __syncthreads();   // XKT build visible for Bf loads

  // per-lane constant W offset (u16 units) — bg-pair waves share lines (L1)
  const int stlane = st * 1024 + lane * 8;

  // seed dist-1 prefetch: ih = 0 (L0, h0)
  short8 Wc0 = *(const short8*)(wt + stlane);
  short8 Wc1 = *(const short8*)(wt + stlane + 512);

  int ih = 0;                          // flat weight-block index = L*39 + h
#pragma unroll 1
  for (int L = 0; L < 3; ++L) {
    // register-cache B-fragments (h-invariant within layer); b = bg*4 + bi
    short8 Bf0[4], Bf1[4];
#pragma unroll
    for (int bi = 0; bi < 4; ++bi) {
      const uint16_t* r = XKT + ((bg * 4 + bi) * 16 + l16) * XKTS + quad * 8;
      Bf0[bi] = *(const short8*)r;          // k 0..31 chunk
      Bf1[bi] = *(const short8*)(r + 32);   // k 32..63 chunk
    }

    floatx4 z[4] = {};
    const floatx4 zero4 = {0.f, 0.f, 0.f, 0.f};

#pragma unroll 3
    for (int h = 0; h < 39; ++h, ++ih) {
      // dist-1 prefetch; uniform SALU base (ih+1 at h=38 IS next layer's h0)
      int ihn = ih + 1;
      if (ihn > 116) ihn = 116;
      const uint16_t* wb = wt + (size_t)ihn * WBLK + stlane;
      short8 Wn0 = *(const short8*)(wb);
      short8 Wn1 = *(const short8*)(wb + 512);

      // x0 scalars; broadcast ds_read_b32, conflict-free (odd stride)
      float xs[4];
#pragma unroll
      for (int bi = 0; bi < 4; ++bi)
        xs[bi] = X0T[((bg * 4 + bi) * 16 + l16) * X0TS + h];

#pragma unroll
      for (int bi = 0; bi < 4; ++bi) {
        floatx4 y = __builtin_amdgcn_mfma_f32_16x16x32_bf16(Wc0, Bf0[bi], zero4, 0, 0, 0);
        y = __builtin_amdgcn_mfma_f32_16x16x32_bf16(Wc1, Bf1[bi], y, 0, 0, 0);
#pragma unroll
        for (int r = 0; r < 4; ++r) z[bi][r] += xs[bi] * y[r];
      }
      Wc0 = Wn0;
      Wc1 = Wn1;
    }

    // ---- epilogue: bias (read here, not held across h-loop) + relu;
    //      xk handoff; sum_d (over l16) -> out ----
    const float* bp = (L == 0) ? bias0 : ((L == 1) ? bias1 : bias2);
#pragma unroll
    for (int bi = 0; bi < 4; ++bi) {
      const int b = bg * 4 + bi;
#pragma unroll
      for (int r = 0; r < 4; ++r) {
        float t = fmaxf(z[bi][r] + bp[st * 16 + quad * 4 + r], 0.f);
        if (L < 2 && st < 4)               // xk = relu(z)[:, :64]; k = s < 64
          XKT[(b * 16 + l16) * XKTS + st * 16 + quad * 4 + r] = f2bf(t);
        float s4 = t;                       // reduce over d = l16 (bits 0..3)
        s4 += __shfl_xor(s4, 1);
        s4 += __shfl_xor(s4, 2);
        s4 += __shfl_xor(s4, 4);
        s4 += __shfl_xor(s4, 8);
        if (l16 == 0) {
          int s = st * 16 + quad * 4 + r;
          // concat: L0 s64:128 -> 0:64 ; L1 s64:128 -> 64:128 ; L2 s -> 128:256
          if (L == 2)       out[(size_t)(bbase + b) * 256 + 128 + s] = s4;
          else if (s >= 64) out[(size_t)(bbase + b) * 256 + L * 64 + (s - 64)] = s4;
        }
      }
    }
    if (L < 2) __syncthreads();   // handoff writes visible before next-layer Bf loads
  }
}

extern "C" void kernel_launch(void* const* d_in, const int* in_sizes, int n_in,
                              void* d_out, int out_size, void* d_ws, size_t ws_size,
                              hipStream_t stream) {
  (void)in_sizes; (void)n_in; (void)out_size; (void)ws_size;
  const float* x  = (const float*)d_in[0];
  const float* w0 = (const float*)d_in[1];
  const float* b0 = (const float*)d_in[2];
  const float* w1 = (const float*)d_in[3];
  const float* b1 = (const float*)d_in[4];
  const float* w2 = (const float*)d_in[5];
  const float* b2 = (const float*)d_in[6];
  uint16_t* wt    = (uint16_t*)d_ws;   // 117 * 8192 * 2 = 1,916,928 B

  cin_prepass<<<NHB2, 256, 0, stream>>>(w0, w1, w2, wt);
  cin_main<<<256, 1024, 0, stream>>>(x, b0, b1, b2, wt, (float*)d_out);
}

// Round 11
// 135.739 us; speedup vs baseline: 2.0082x; 1.0168x over previous
//
#include <hip/hip_runtime.h>
#include <stdint.h>
#include <stddef.h>

// ---------------- problem constants ----------------
// B=2048, F0=39, D=16, layers 128/128/128, xk halves to 64 after each layer.
// Factored form: y_h[s,d] = sum_k W[h,k,s]*xk[b,k,d] (MFMA: A=W static, B=xk
// h-invariant -> register-cached per layer); z[b,s,d] = sum_h x0[b,h,d]*y_h[s,d].
// R22: R21 + the two remaining latency trims. Ledger:
//  - R21 (unroll3, bias->epilogue): steady 74.9us, VGPR 60, zero spill.
//  - R19 (unroll3 + xs prefetch + bvr held): steady 74.1us but 2-dword spill
//    (64+2) -> 178us dispatch-0. R21 freed 4 regs (bvr) -> xs prefetch now
//    fits: expected ~62 regs, no spill, both gains.
//  - z-combine written as float2 vector ops -> v_pk_fma_f32 (gfx90a+): 16
//    fmac -> 8 pk_fma, -64 cyc/SIMD-step VALU issue.
// Wall model per SIMD-h (1537 cyc): matrix 620, VALU 420 (fmac 128 + AGPR
// churn), LDS 100, ~400 dead (xs ds_read latency + W exposure). This round
// attacks the dead cycles + VALU issue; falsifier: WRITE_SIZE must stay
// 2048KB (4096 = spill -> revert).
// Kept: X0TS=45 (conflicts 4.69M->0.69M), flat-ih SALU W walk, h=39 drop,
// grid 256 (1 block/CU; 2 blocks/CU thrash W L1 - R12/R13), bg-pair W
// sharing, dist-1 W register prefetch, unroll 3 (39=13x3).
#define F0N  39
#define SN   128
#define NB   8             // batches per block
#define X0TS 45            // f32 stride of X0T row (b,d): 39+6 pad, odd => conflict-free
#define XKTS 72            // u16 stride of XKT row (b,d): 64+8 pad, 16B-aligned
#define WBLK 8192          // u16 per (L,h) W block: 8 s-tiles x 2 chunks x 512
#define NHB2 234           // 3*39*2 prepass blocks (one per (L,h,k-half))

typedef __attribute__((ext_vector_type(8))) short short8;   // MFMA A/B operand
typedef __attribute__((ext_vector_type(4))) float floatx4;  // MFMA accumulator
typedef __attribute__((ext_vector_type(2))) float floatx2;  // pk_fma pair

__device__ __forceinline__ uint16_t f2bf(float f) {         // RNE f32->bf16
  uint32_t u = __float_as_uint(f);
  u += 0x7fffu + ((u >> 16) & 1u);
  return (uint16_t)(u >> 16);
}

// ---------------- pre-pass: W fp32 -> bf16 A-fragment blocks ----------------
// One block per (L,h,ch). Output layout identical to R6-R21 (verified):
//   wt[(L*39+h)*WBLK + (st*2+ch)*512 + lane*8 + j],
//   value = W[h][k=ch*32+quad*8+j][s=st*16+l16].
__global__ __launch_bounds__(256) void cin_prepass(
    const float* __restrict__ w0, const float* __restrict__ w1,
    const float* __restrict__ w2, uint16_t* __restrict__ wt) {
  __shared__ float T[32 * 132];               // [k_local][s], +4 pad floats/row
  const int bc = blockIdx.x;                  // 0..233
  const int ch = bc & 1;
  const int lh = bc >> 1;                     // 0..116
  const int L = lh / F0N;
  const int h = lh - L * F0N;
  const float* W = (L == 0) ? w0 : ((L == 1) ? w1 : w2);
  const int fk = (L == 0) ? 39 : 64;
  const int tid = threadIdx.x;

  for (int e = tid; e < 4096; e += 256) {     // coalesced fp32 read
    int kc = e >> 7, s = e & 127;
    int k = ch * 32 + kc;
    T[kc * 132 + s] = (k < fk) ? W[(h * fk + k) * SN + s] : 0.0f;
  }
  __syncthreads();
  uint32_t* dst = (uint32_t*)(wt + (size_t)lh * WBLK);
  for (int i = tid; i < 2048; i += 256) {     // coalesced u32 writes, frag order
    int st = i >> 8, w = i & 255;
    int ln = w >> 2, jp = w & 3;
    int quad = ln >> 4, l16 = ln & 15;
    int k0 = quad * 8 + jp * 2;               // local k within this half
    int s = st * 16 + l16;
    dst[(size_t)(st * 2 + ch) * 256 + w] =
        (uint32_t)f2bf(T[k0 * 132 + s]) | ((uint32_t)f2bf(T[(k0 + 1) * 132 + s]) << 16);
  }
}

// ---------------- fused main kernel ----------------
// 256 blocks x 1024 threads (16 waves), 1 block/CU, 4 waves/SIMD.
// Block owns NB=8 batches x full s (xk handoff block-local). Wave (st,bg):
// s-tile [st*16,st*16+16) x batches [bg*4, bg*4+4). Per layer: Bf register-
// cached; per h (unroll 3): dist-1 W prefetch (SALU ih base), dist-1 xs
// prefetch (layer rollover), 8 MFMA + 8 pk_fma. Flat weight index ih =
// L*39+h in [0,117); prefetch min(ih+1,116) rolls into next layer's h0 at
// h=38. D-layout: D[s=st*16+quad*4+r][d=l16]; sum_d over l16 bits.
__global__ __launch_bounds__(1024) void cin_main(
    const float* __restrict__ x,       // (2048, 39, 16) fp32
    const float* __restrict__ bias0, const float* __restrict__ bias1,
    const float* __restrict__ bias2,
    const uint16_t* __restrict__ wt,   // A-frag bf16 weights (d_ws)
    float* __restrict__ out) {         // (2048, 256) fp32

  __shared__ __align__(16) float    X0T[NB * 16 * X0TS];  // x0[b][d][h] f32, 23040 B
  __shared__ __align__(16) uint16_t XKT[NB * 16 * XKTS];  // xk[b][d][k] bf16, 18432 B

  const int tid  = threadIdx.x;
  const int lane = tid & 63;
  const int wave = tid >> 6;           // 0..15
  const int st   = wave >> 1;          // s-tile 0..7
  const int bg   = wave & 1;           // batch group 0..1
  const int l16  = lane & 15;          // = d (output col)
  const int quad = lane >> 4;
  const int bbase = blockIdx.x * NB;

  // zero X0T (h-pad 39..44 must be 0) and XKT (k-pad for L0)
  {
    float* p = X0T;
#pragma unroll
    for (int i = 0; i < 6; i++) { int e = tid + 1024 * i; if (e < NB * 16 * X0TS) p[e] = 0.f; }
    uint32_t* q = (uint32_t*)XKT;
#pragma unroll
    for (int i = 0; i < 5; i++) { int e = tid + 1024 * i; if (e < NB * 16 * XKTS / 2) q[e] = 0u; }
  }
  __syncthreads();

  // fill X0T[b][d][h] = x[bbase+b][h][d]  (coalesced read, LDS transpose-scatter)
#pragma unroll
  for (int it = 0; it < 5; ++it) {
    int e = tid + it * 1024;           // e = (b*39 + h)*16 + d, total 4992
    if (e < NB * F0N * 16) {
      float v = x[(size_t)bbase * (F0N * 16) + e];
      int d = e & 15, p = e >> 4;
      int b = p / F0N, h = p - b * F0N;
      X0T[(b * 16 + d) * X0TS + h] = v;
    }
  }
  __syncthreads();

  // build layer-0 XKT[b][d][k] = bf16(x0[b][k][d]) for k<39, 0 for k in [39,64)
  if (tid < 512) {
    int b = tid >> 6, d = (tid >> 2) & 15, kg = tid & 3;
    const float* src = &X0T[(b * 16 + d) * X0TS];
    uint32_t* drow = (uint32_t*)&XKT[(b * 16 + d) * XKTS + kg * 16];
#pragma unroll
    for (int i2 = 0; i2 < 8; i2++) {
      int k0 = kg * 16 + i2 * 2;
      uint32_t lo = (k0 < 39)     ? (uint32_t)f2bf(src[k0])     : 0u;
      uint32_t hi = (k0 + 1 < 39) ? (uint32_t)f2bf(src[k0 + 1]) : 0u;
      drow[i2] = lo | (hi << 16);
    }
  }
  __syncthreads();   // XKT build visible for Bf loads

  // per-lane constant W offset (u16 units) — bg-pair waves share lines (L1)
  const int stlane = st * 1024 + lane * 8;

  // per-(bi) x0 LDS element offsets (int, not pointers: 4 regs)
  int xoff[4];
#pragma unroll
  for (int bi = 0; bi < 4; ++bi)
    xoff[bi] = ((bg * 4 + bi) * 16 + l16) * X0TS;

  // seed dist-1 prefetches: ih = 0 (L0, h0); xs at h=0
  short8 Wc0 = *(const short8*)(wt + stlane);
  short8 Wc1 = *(const short8*)(wt + stlane + 512);
  float xsc[4];
#pragma unroll
  for (int bi = 0; bi < 4; ++bi) xsc[bi] = X0T[xoff[bi]];

  int ih = 0;                          // flat weight-block index = L*39 + h
#pragma unroll 1
  for (int L = 0; L < 3; ++L) {
    // register-cache B-fragments (h-invariant within layer); b = bg*4 + bi
    short8 Bf0[4], Bf1[4];
#pragma unroll
    for (int bi = 0; bi < 4; ++bi) {
      const uint16_t* r = XKT + ((bg * 4 + bi) * 16 + l16) * XKTS + quad * 8;
      Bf0[bi] = *(const short8*)r;          // k 0..31 chunk
      Bf1[bi] = *(const short8*)(r + 32);   // k 32..63 chunk
    }

    floatx4 z[4] = {};
    const floatx4 zero4 = {0.f, 0.f, 0.f, 0.f};

#pragma unroll 3
    for (int h = 0; h < 39; ++h, ++ih) {
      // dist-1 W prefetch; uniform SALU base (ih+1 at h=38 IS next layer's h0)
      int ihn = ih + 1;
      if (ihn > 116) ihn = 116;
      const uint16_t* wb = wt + (size_t)ihn * WBLK + stlane;
      short8 Wn0 = *(const short8*)(wb);
      short8 Wn1 = *(const short8*)(wb + 512);

      // dist-1 xs prefetch; x0 is layer-invariant so h=38 rolls to h=0
      int hn = (h == 38) ? 0 : h + 1;
      float xsn[4];
#pragma unroll
      for (int bi = 0; bi < 4; ++bi) xsn[bi] = X0T[xoff[bi] + hn];

#pragma unroll
      for (int bi = 0; bi < 4; ++bi) {
        floatx4 y = __builtin_amdgcn_mfma_f32_16x16x32_bf16(Wc0, Bf0[bi], zero4, 0, 0, 0);
        y = __builtin_amdgcn_mfma_f32_16x16x32_bf16(Wc1, Bf1[bi], y, 0, 0, 0);
        // packed combine: float2 ops -> v_pk_fma_f32 (8 instead of 16 fmac)
        floatx2 xv = {xsc[bi], xsc[bi]};
        floatx2* zp = (floatx2*)&z[bi];
        const floatx2* yp = (const floatx2*)&y;
        zp[0] += xv * yp[0];
        zp[1] += xv * yp[1];
      }
      Wc0 = Wn0;
      Wc1 = Wn1;
#pragma unroll
      for (int bi = 0; bi < 4; ++bi) xsc[bi] = xsn[bi];
    }

    // ---- epilogue: bias (read here, not held across h-loop) + relu;
    //      xk handoff; sum_d (over l16) -> out ----
    const float* bp = (L == 0) ? bias0 : ((L == 1) ? bias1 : bias2);
#pragma unroll
    for (int bi = 0; bi < 4; ++bi) {
      const int b = bg * 4 + bi;
#pragma unroll
      for (int r = 0; r < 4; ++r) {
        float t = fmaxf(z[bi][r] + bp[st * 16 + quad * 4 + r], 0.f);
        if (L < 2 && st < 4)               // xk = relu(z)[:, :64]; k = s < 64
          XKT[(b * 16 + l16) * XKTS + st * 16 + quad * 4 + r] = f2bf(t);
        float s4 = t;                       // reduce over d = l16 (bits 0..3)
        s4 += __shfl_xor(s4, 1);
        s4 += __shfl_xor(s4, 2);
        s4 += __shfl_xor(s4, 4);
        s4 += __shfl_xor(s4, 8);
        if (l16 == 0) {
          int s = st * 16 + quad * 4 + r;
          // concat: L0 s64:128 -> 0:64 ; L1 s64:128 -> 64:128 ; L2 s -> 128:256
          if (L == 2)       out[(size_t)(bbase + b) * 256 + 128 + s] = s4;
          else if (s >= 64) out[(size_t)(bbase + b) * 256 + L * 64 + (s - 64)] = s4;
        }
      }
    }
    if (L < 2) __syncthreads();   // handoff writes visible before next-layer Bf loads
  }
}

extern "C" void kernel_launch(void* const* d_in, const int* in_sizes, int n_in,
                              void* d_out, int out_size, void* d_ws, size_t ws_size,
                              hipStream_t stream) {
  (void)in_sizes; (void)n_in; (void)out_size; (void)ws_size;
  const float* x  = (const float*)d_in[0];
  const float* w0 = (const float*)d_in[1];
  const float* b0 = (const float*)d_in[2];
  const float* w1 = (const float*)d_in[3];
  const float* b1 = (const float*)d_in[4];
  const float* w2 = (const float*)d_in[5];
  const float* b2 = (const float*)d_in[6];
  uint16_t* wt    = (uint16_t*)d_ws;   // 117 * 8192 * 2 = 1,916,928 B

  cin_prepass<<<NHB2, 256, 0, stream>>>(w0, w1, w2, wt);
  cin_main<<<256, 1024, 0, stream>>>(x, b0, b1, b2, wt, (float*)d_out);
}